// Round 4
// baseline (678.758 us; speedup 1.0000x reference)
//
#include <hip/hip_runtime.h>
#include <math.h>

// HMLSTMOutput — fp32 in/out buffers; internal bf16 MFMA.
// R10: structural stall-hiding via TWO independent blocks/CU (R8/R9 had 1 block/CU —
// 128KB LDS — so the lockstep read-phase/MFMA-phase serialization idled one pipe at all
// times: measured 6230 cyc/tile vs ~2500 floor, arithmetic in journal). New GEMM config:
// BM=128, BN=256, BK=32, 4 waves (1 wave/SIMD), wave tile 128x64 (same bytes/FLOP),
// LDS 48KB double-buffered -> 2 blocks/CU by LDS; __launch_bounds__(256,2) caps regs at
// 256/wave -> 2 waves/SIMD = 2 blocks/CU by VGPR. Sibling block's port traffic overlaps
// my MFMA and vice versa. Per block-tile: port 576 cyc vs MFMA 620 cyc/SIMD (balanced).
// Simple depth-1 loop: stage T+1 (6 DMAs/wave) -> reads+MFMA (A-frags read-ahead by 4)
// -> vmcnt(0)+barrier. BN=256 keeps A re-reads at 4x (L3), B (3MB) L2-resident.

typedef __attribute__((ext_vector_type(8))) short short8;   // 8 bf16 = 4 VGPRs (MFMA A/B frag)
typedef __attribute__((ext_vector_type(4))) float float4v;  // MFMA C/D frag

#define DEV __device__ __forceinline__

DEV unsigned short f2bf(float f){
    union{float f; unsigned int i;} c; c.f = f;
    unsigned int r = c.i + 0x7fffu + ((c.i>>16)&1u);   // round-to-nearest-even
    return (unsigned short)(r>>16);
}
DEV unsigned int pack2(float a, float b){
    return (unsigned int)f2bf(a) | ((unsigned int)f2bf(b)<<16);
}

// direct global->LDS DMA, 16 B per lane; LDS dest = wave-uniform base + lane*16
DEV void gload_lds16(const unsigned short* g, unsigned short* l){
    __builtin_amdgcn_global_load_lds((const __attribute__((address_space(1))) void*)g,
                                     (__attribute__((address_space(3))) void*)l, 16, 0, 0);
}

// ---------------- fused prep: gates+u and all weight converts (1 launch) ----------------
__global__ __launch_bounds__(256) void prep(
    const float* __restrict__ x,  const float* __restrict__ Wg,
    const float* __restrict__ W1, const float* __restrict__ W2,
    const float* __restrict__ Wo, const float* __restrict__ We,
    unsigned short* __restrict__ u,   unsigned short* __restrict__ W1b,
    unsigned short* __restrict__ W2b, unsigned short* __restrict__ Wob,
    unsigned short* __restrict__ Wep)
{
    int b = blockIdx.x;
    if(b < 8192){
        int row  = b*4 + (threadIdx.x>>6);
        int lane = threadIdx.x & 63;
        const float4* xr = (const float4*)(x + (size_t)row*1536);
        float4 hv[6];
        #pragma unroll
        for(int j=0;j<6;j++) hv[j] = xr[j*64 + lane];

        float p[3];
        #pragma unroll
        for(int l=0;l<3;l++){
            const float4* wr = (const float4*)(Wg + (size_t)l*1536);
            float s = 0.f;
            #pragma unroll
            for(int j=0;j<6;j++){
                float4 wv = wr[j*64 + lane];
                s += hv[j].x*wv.x + hv[j].y*wv.y + hv[j].z*wv.z + hv[j].w*wv.w;
            }
            p[l] = s;
        }
        #pragma unroll
        for(int off=32; off; off>>=1){
            p[0] += __shfl_xor(p[0], off);
            p[1] += __shfl_xor(p[1], off);
            p[2] += __shfl_xor(p[2], off);
        }
        float g[3];
        #pragma unroll
        for(int l=0;l<3;l++) g[l] = 1.f/(1.f + __expf(-p[l]));

        uint2* ur = (uint2*)(u + (size_t)row*1536);
        #pragma unroll
        for(int j=0;j<6;j++){
            float gj = g[(j*64+lane)>>7];   // float4 f=j*64+lane covers [4f,4f+4) -> chunk f>>7
            uint2 o;
            o.x = pack2(hv[j].x*gj, hv[j].y*gj);
            o.y = pack2(hv[j].z*gj, hv[j].w*gj);
            ur[j*64 + lane] = o;
        }
        return;
    }
    b -= 8192;
    if(b < 1280){
        const float* src; unsigned short* dst; int v0;
        if(b < 512)      { src = W1; dst = W1b; v0 = b<<8; }
        else if(b < 1024){ src = W2; dst = W2b; v0 = (b-512)<<8; }
        else             { src = Wo; dst = Wob; v0 = (b-1024)<<8; }
        int v = v0 + threadIdx.x;
        const float4* s = (const float4*)(src) + (size_t)v*2;
        float4 a = s[0], c = s[1];
        uint4 o;
        o.x = pack2(a.x, a.y); o.y = pack2(a.z, a.w);
        o.z = pack2(c.x, c.y); o.w = pack2(c.z, c.w);
        *((uint4*)dst + v) = o;
        return;
    }
    b -= 1280;
    int v  = b*256 + threadIdx.x;   // 196608 vectors of 8 elems
    int i8 = v & 63;
    int e  = (v>>6) & 1023;
    int l  = v>>16;
    const float4* s = (const float4*)(We + (size_t)l*524288 + (size_t)e*512 + i8*8);
    float4 a = s[0], c = s[1];
    uint4 o;
    o.x = pack2(a.x, a.y); o.y = pack2(a.z, a.w);
    o.z = pack2(c.x, c.y); o.w = pack2(c.z, c.w);
    *(uint4*)(Wep + (size_t)e*1536 + (size_t)l*512 + i8*8) = o;
}

// ---- GEMM: C[M,N] = act(A[M,K] @ W[N,K]^T + bias)  (bf16 in, fp32 acc) ----
// BM=128, BN=256, BK=32, 4 waves (wave wn=wid owns n-slice wid*64), wave out 128x64
// = acc[8][4] 16x16 frags. Double-buffered 48KB LDS, XOR swizzle slot = cb^(r&3)
// (2-way max on b128 reads = free). 2 blocks/CU co-resident for cross-block overlap.
template<int ACT, int BIAS_ROWS, bool F32OUT>
__global__ __launch_bounds__(256, 2) void gemm_bt2(
    const unsigned short* __restrict__ A,
    const unsigned short* __restrict__ W,
    const float* __restrict__ bias,
    void* __restrict__ Cv,
    int M, int N, int K)
{
    __shared__ __align__(128) unsigned short As[2*128*32];   // 16 KB (2 parities)
    __shared__ __align__(128) unsigned short Bs[2*256*32];   // 32 KB

    const int tid = threadIdx.x;
    const int nb  = N >> 8;            // n-tiles (BN=256)
    const int mt  = M >> 7;            // m-tiles (BM=128), divisible by 8
    const int xcd = blockIdx.x & 7;    // XCD-exclusive bm range (bijective: grid%8==0)
    const int j   = blockIdx.x >> 3;
    const int bm  = xcd*(mt>>3) + j/nb;
    const int bn  = j % nb;
    const int m0  = bm << 7, n0 = bn << 8;

    const int lane = tid & 63, wid = tid >> 6;      // 4 waves; wave's n-slice = wid*64
    const int lr = lane & 15, quad = lane >> 4;
    const int cread = ((quad ^ (lr & 3)) * 8);      // swizzled col-block for frag reads
    const int rl  = lane >> 2;                      // staging: row within 16-row macro
    const int cbl = (lane & 3) ^ (rl & 3);          // pre-swizzled source col-block
    const size_t aoff = (size_t)rl*K + cbl*8;
    const int nt = K >> 5;                          // 48 or 32 (even)

    float4v acc[8][4];
    #pragma unroll
    for(int i=0;i<8;i++)
        #pragma unroll
        for(int jj=0;jj<4;jj++) acc[i][jj] = (float4v){0.f,0.f,0.f,0.f};

    // stage one 16-row macro (1 KB): A has 8 macros (2/wave), B has 16 (4/wave).
    // LDS dest linear; swizzle realized via source addr: slot s at row r holds cb = s^(r&3).
#define STAGE_A(d,s,P) gload_lds16(A + ((size_t)(m0 + (wid*2+(d))*16))*K + (size_t)(s)*32 + aoff, \
                                   &As[(P)*4096 + ((wid*2+(d))*16)*32])
#define STAGE_B(d,s,P) gload_lds16(W + ((size_t)(n0 + (wid*4+(d))*16))*K + (size_t)(s)*32 + aoff, \
                                   &Bs[(P)*8192 + ((wid*4+(d))*16)*32])
#define STAGE_ALL(s,P) do{ STAGE_A(0,s,P); STAGE_A(1,s,P); \
    STAGE_B(0,s,P); STAGE_B(1,s,P); STAGE_B(2,s,P); STAGE_B(3,s,P); }while(0)

#define READ_AF(mi) af[mi] = *(const short8*)&Ap[(mi)*512 + lr*32 + cread]
#define MFMA_MI(mi) do{ \
    acc[mi][0] = __builtin_amdgcn_mfma_f32_16x16x32_bf16(af[mi], bfr[0], acc[mi][0], 0,0,0); \
    acc[mi][1] = __builtin_amdgcn_mfma_f32_16x16x32_bf16(af[mi], bfr[1], acc[mi][1], 0,0,0); \
    acc[mi][2] = __builtin_amdgcn_mfma_f32_16x16x32_bf16(af[mi], bfr[2], acc[mi][2], 0,0,0); \
    acc[mi][3] = __builtin_amdgcn_mfma_f32_16x16x32_bf16(af[mi], bfr[3], acc[mi][3], 0,0,0); }while(0)

    // ---- prologue: stage tile 0 into parity 0, drain, sync ----
    STAGE_ALL(0,0);
    asm volatile("s_waitcnt vmcnt(0)" ::: "memory");
    __builtin_amdgcn_s_barrier();

    for(int tt=0; tt<nt; tt+=2){
        #pragma unroll
        for(int uu=0; uu<2; ++uu){
            const int T = tt + uu;                  // runtime tile index; uu = parity (static)
            // issue next tile's DMAs first (in flight for the whole tile's compute)
            if(T+1 < nt) STAGE_ALL(T+1, 1-uu);
            __builtin_amdgcn_sched_barrier(0);      // pin: DMAs issue before the read burst

            const unsigned short* Ap = &As[uu*4096];
            const unsigned short* Bp = &Bs[uu*8192 + wid*2048];  // wave's 64 B rows
            short8 af[8], bfr[4];
            bfr[0] = *(const short8*)&Bp[        lr*32 + cread];
            bfr[1] = *(const short8*)&Bp[ 512 +  lr*32 + cread];
            bfr[2] = *(const short8*)&Bp[1024 +  lr*32 + cread];
            bfr[3] = *(const short8*)&Bp[1536 +  lr*32 + cread];
            READ_AF(0); READ_AF(1); READ_AF(2); READ_AF(3);
            __builtin_amdgcn_s_setprio(1);
            MFMA_MI(0); READ_AF(4);
            MFMA_MI(1); READ_AF(5);
            MFMA_MI(2); READ_AF(6);
            MFMA_MI(3); READ_AF(7);
            MFMA_MI(4); MFMA_MI(5); MFMA_MI(6); MFMA_MI(7);
            __builtin_amdgcn_s_setprio(0);

            // boundary: own 6 DMAs for T+1 must have landed before anyone reads parity 1-uu
            if(T+1 < nt){
                asm volatile("s_waitcnt vmcnt(0)" ::: "memory");
                __builtin_amdgcn_s_barrier();
            }
        }
    }
#undef STAGE_A
#undef STAGE_B
#undef STAGE_ALL
#undef READ_AF
#undef MFMA_MI

    // epilogue: C/D layout col(n)=lane&15, row(m)=quad*4+reg (m89/m91-verified)
    #pragma unroll
    for(int ni=0; ni<4; ++ni){
        const int n = n0 + wid*64 + ni*16 + lr;
        float bsum = 0.f;
        #pragma unroll
        for(int r=0; r<BIAS_ROWS; ++r) bsum += bias[(size_t)r*N + n];
        #pragma unroll
        for(int Q=0; Q<8; ++Q){
            #pragma unroll
            for(int reg=0; reg<4; ++reg){
                const int m = m0 + Q*16 + quad*4 + reg;
                float v = acc[Q][ni][reg] + bsum;
                if(ACT==1)      v = fmaxf(v, 0.f);
                else if(ACT==2) v = tanhf(v);
                if constexpr (F32OUT) ((float*)Cv)[(size_t)m*N + n] = v;
                else                  ((unsigned short*)Cv)[(size_t)m*N + n] = f2bf(v);
            }
        }
    }
}

extern "C" void kernel_launch(void* const* d_in, const int* in_sizes, int n_in,
                              void* d_out, int out_size, void* d_ws, size_t ws_size,
                              hipStream_t stream)
{
    const float* x  = (const float*)d_in[0];
    const float* Wg = (const float*)d_in[1];
    const float* We = (const float*)d_in[2];
    const float* be = (const float*)d_in[3];
    const float* W1 = (const float*)d_in[4];
    const float* b1 = (const float*)d_in[5];
    const float* W2 = (const float*)d_in[6];
    const float* b2 = (const float*)d_in[7];
    const float* Wo = (const float*)d_in[8];
    const float* bo = (const float*)d_in[9];
    float* out = (float*)d_out;

    const int M = 32768;    // B*T

    // workspace: 8 MB weights + 96 MB slotA + 64 MB slotB = 168 MB
    char* w = (char*)d_ws;
    unsigned short* Wep   = (unsigned short*)w; w += (size_t)1024*1536*2;  //  3 MB
    unsigned short* W1b   = (unsigned short*)w; w += (size_t)1024*1024*2;  //  2 MB
    unsigned short* W2b   = (unsigned short*)w; w += (size_t)1024*1024*2;  //  2 MB
    unsigned short* Wob   = (unsigned short*)w; w += (size_t)512*1024*2;   //  1 MB
    unsigned short* slotA = (unsigned short*)w; w += (size_t)M*1536*2;     // 96 MB
    unsigned short* slotB = (unsigned short*)w; w += (size_t)M*1024*2;     // 64 MB
    unsigned short* u  = slotA;   // [M,1536]
    unsigned short* o1 = slotA;   // [M,1024] (u dead after GEMM-1)
    unsigned short* he = slotB;   // [M,1024]
    unsigned short* o2 = slotB;   // [M,1024] (he dead after GEMM-2)

    hipLaunchKernelGGL(prep, dim3(10240), dim3(256), 0, stream,
                       x, Wg, W1, W2, Wo, We, u, W1b, W2b, Wob, Wep);

    // grids: (M/128)*(N/256); all %8 == 0 for the XCD swizzle
    hipLaunchKernelGGL((gemm_bt2<1,3,false>), dim3((M/128)*(1024/256)), dim3(256), 0, stream,
                       u,  Wep, be, he,  M, 1024, 1536);
    hipLaunchKernelGGL((gemm_bt2<2,1,false>), dim3((M/128)*(1024/256)), dim3(256), 0, stream,
                       he, W1b, b1, o1,  M, 1024, 1024);
    hipLaunchKernelGGL((gemm_bt2<2,1,false>), dim3((M/128)*(1024/256)), dim3(256), 0, stream,
                       o1, W2b, b2, o2,  M, 1024, 1024);
    hipLaunchKernelGGL((gemm_bt2<0,1,true>),  dim3((M/128)*(512/256)),  dim3(256), 0, stream,
                       o2, Wob, bo, out, M, 512, 1024);
}

// Round 5
// 661.523 us; speedup vs baseline: 1.0261x; 1.0261x over previous
//
#include <hip/hip_runtime.h>
#include <math.h>

// HMLSTMOutput — fp32 in/out buffers; internal bf16 MFMA.
// R11: B-OFF-THE-LDS-PORT. R8-R10 post-mortems: LDS port (256KB/tile ~2-3kcyc) is the
// same magnitude as MFMA (2.5kcyc/tile) -> every schedule serializes or co-bottlenecks.
// Weights are 2-3MB (per-XCD L2-resident) and re-read by 256 blocks, so B is pre-packed
// into MFMA-frag order by prep, and each wave global-loads B-frags straight from L2 into
// registers (coalesced 1KB loads, double-buffered 1 tile ahead). LDS carries A only:
// BM=128,BN=256,BK=64, 4 waves, 32KB LDS -> per block-tile port 80KB (~940cyc) vs MFMA
// 1242cyc -> MFMA-bound; 2 independent blocks/CU overlap each other's stalls.
// R10's BK=32 swizzle bug (rows 4 apart alias banks -> 4-way, 9.4M conflicts) fixed by
// returning to R8's BK=64 scheme (measured 0 conflicts).
// vmcnt: per tile issue [4 A-DMA(T+1)][8 B-load(T+1)]; boundary vmcnt(8) keeps B in
// flight; compiler's counted waits gate B use (loaded 12 ops earlier).

typedef __attribute__((ext_vector_type(8))) short short8;   // 8 bf16 = 4 VGPRs (MFMA A/B frag)
typedef __attribute__((ext_vector_type(4))) float float4v;  // MFMA C/D frag

#define DEV __device__ __forceinline__

DEV unsigned short f2bf(float f){
    union{float f; unsigned int i;} c; c.f = f;
    unsigned int r = c.i + 0x7fffu + ((c.i>>16)&1u);   // round-to-nearest-even
    return (unsigned short)(r>>16);
}
DEV unsigned int pack2(float a, float b){
    return (unsigned int)f2bf(a) | ((unsigned int)f2bf(b)<<16);
}

// direct global->LDS DMA, 16 B per lane; LDS dest = wave-uniform base + lane*16
DEV void gload_lds16(const unsigned short* g, unsigned short* l){
    __builtin_amdgcn_global_load_lds((const __attribute__((address_space(1))) void*)g,
                                     (__attribute__((address_space(3))) void*)l, 16, 0, 0);
}

// ---------------- fused prep: gates+u and all weight converts (1 launch) ----------------
// blocks [0,8192): gate_u (4 rows each)
// blocks [8192,9472): W1/W2/Wo fp32 -> FRAG-PACKED bf16 (512+512+256 blocks)
// blocks [9472,10240): We [3,1024,512] -> FRAG-PACKED Wep (N=1024,K=1536)
// Frag pack: P[f][l][j], f=nf*(K/32)+ks; element = W[nf*16+(l&15)][ks*32+(l>>4)*8+j].
// A wave's b128 load of frag f is then 64 consecutive 16B chunks (perfect coalesce).
__global__ __launch_bounds__(256) void prep(
    const float* __restrict__ x,  const float* __restrict__ Wg,
    const float* __restrict__ W1, const float* __restrict__ W2,
    const float* __restrict__ Wo, const float* __restrict__ We,
    unsigned short* __restrict__ u,   unsigned short* __restrict__ W1b,
    unsigned short* __restrict__ W2b, unsigned short* __restrict__ Wob,
    unsigned short* __restrict__ Wep)
{
    int b = blockIdx.x;
    if(b < 8192){
        int row  = b*4 + (threadIdx.x>>6);
        int lane = threadIdx.x & 63;
        const float4* xr = (const float4*)(x + (size_t)row*1536);
        float4 hv[6];
        #pragma unroll
        for(int j=0;j<6;j++) hv[j] = xr[j*64 + lane];

        float p[3];
        #pragma unroll
        for(int l=0;l<3;l++){
            const float4* wr = (const float4*)(Wg + (size_t)l*1536);
            float s = 0.f;
            #pragma unroll
            for(int j=0;j<6;j++){
                float4 wv = wr[j*64 + lane];
                s += hv[j].x*wv.x + hv[j].y*wv.y + hv[j].z*wv.z + hv[j].w*wv.w;
            }
            p[l] = s;
        }
        #pragma unroll
        for(int off=32; off; off>>=1){
            p[0] += __shfl_xor(p[0], off);
            p[1] += __shfl_xor(p[1], off);
            p[2] += __shfl_xor(p[2], off);
        }
        float g[3];
        #pragma unroll
        for(int l=0;l<3;l++) g[l] = 1.f/(1.f + __expf(-p[l]));

        uint2* ur = (uint2*)(u + (size_t)row*1536);
        #pragma unroll
        for(int j=0;j<6;j++){
            float gj = g[(j*64+lane)>>7];   // float4 f=j*64+lane covers [4f,4f+4) -> chunk f>>7
            uint2 o;
            o.x = pack2(hv[j].x*gj, hv[j].y*gj);
            o.y = pack2(hv[j].z*gj, hv[j].w*gj);
            ur[j*64 + lane] = o;
        }
        return;
    }
    b -= 8192;
    if(b < 1280){
        // frag-pack W1/W2/Wo (all K=1024, K/32=32). v = f*64 + l; dst uint4 index = v.
        const float* src; unsigned short* dst; int v0;
        if(b < 512)      { src = W1; dst = W1b; v0 = b<<8; }
        else if(b < 1024){ src = W2; dst = W2b; v0 = (b-512)<<8; }
        else             { src = Wo; dst = Wob; v0 = (b-1024)<<8; }
        int v  = v0 + threadIdx.x;
        int l  = v & 63;
        int f  = v >> 6;
        int ks = f & 31;
        int nf = f >> 5;
        int n  = nf*16 + (l&15);
        int k  = ks*32 + ((l>>4)<<3);
        const float4* s = (const float4*)(src + (size_t)n*1024 + k);
        float4 a = s[0], c = s[1];
        uint4 o;
        o.x = pack2(a.x, a.y); o.y = pack2(a.z, a.w);
        o.z = pack2(c.x, c.y); o.w = pack2(c.z, c.w);
        *((uint4*)dst + v) = o;
        return;
    }
    b -= 1280;
    {   // frag-pack Wep: N=1024, K=1536 (K/32=48). src We[layer][e][i], k=layer*512+i.
        int v  = b*256 + threadIdx.x;   // 196608
        int l  = v & 63;
        int f  = v >> 6;                // 0..3071
        int ks = f % 48;
        int nf = f / 48;
        int e  = nf*16 + (l&15);
        int dk = ks*32 + ((l>>4)<<3);
        int layer = dk >> 9;
        int i  = dk & 511;
        const float4* s = (const float4*)(We + (size_t)layer*524288 + (size_t)e*512 + i);
        float4 a = s[0], c = s[1];
        uint4 o;
        o.x = pack2(a.x, a.y); o.y = pack2(a.z, a.w);
        o.z = pack2(c.x, c.y); o.w = pack2(c.z, c.w);
        *((uint4*)Wep + v) = o;
        return;
    }
}

// ---- GEMM: C[M,N] = act(A[M,K] @ W[N,K]^T + bias); W is FRAG-PACKED bf16 ----
// BM=128, BN=256, BK=64, 4 waves; wave wid owns n-slice [wid*64, wid*64+64).
// A: LDS double-buffered 32KB, R8 XOR swizzle (slot cb at row r = cb^(r&7), 0-conflict).
// B: straight from L2 in frag order into registers, double-buffered 1 tile ahead.
template<int ACT, int BIAS_ROWS, bool F32OUT>
__global__ __launch_bounds__(256, 2) void gemm_bd(
    const unsigned short* __restrict__ A,
    const unsigned short* __restrict__ Wp,   // frag-packed
    const float* __restrict__ bias,
    void* __restrict__ Cv,
    int M, int N, int K)
{
    __shared__ __align__(128) unsigned short As[2*128*64];   // 32 KB (2 parities)

    const int tid = threadIdx.x;
    const int nb  = N >> 8;            // n-tiles (BN=256)
    const int mt  = M >> 7;            // m-tiles (BM=128), divisible by 8
    const int xcd = blockIdx.x & 7;    // XCD-exclusive bm range (bijective: grid%8==0)
    const int j   = blockIdx.x >> 3;
    const int bm  = xcd*(mt>>3) + j/nb;
    const int bn  = j % nb;
    const int m0  = bm << 7, n0 = bn << 8;

    const int lane = tid & 63, wid = tid >> 6;      // 4 waves
    const int lr = lane & 15, quad = lane >> 4, sx = lr & 7;
    const int srow = lane >> 3;                     // staging: row within 8-row slice
    const int scb  = (lane & 7) ^ srow;             // pre-swizzled source col-block
    const size_t aoff = (size_t)srow*K + scb*8;
    const int KS = K >> 5;                          // frags per n-row of 16
    const int nf0 = (n0 >> 4) + wid*4;              // wave's first n-frag
    const int nt = K >> 6;                          // 24 or 16 (even)
    const short8* Bfp = (const short8*)Wp;          // frag-packed: idx = f*64 + lane

    float4v acc[8][4];
    #pragma unroll
    for(int i=0;i<8;i++)
        #pragma unroll
        for(int jj=0;jj<4;jj++) acc[i][jj] = (float4v){0.f,0.f,0.f,0.f};

    // A staging: wave wid covers rows [wid*32, wid*32+32) as 4 DMAs of 8 rows.
#define STAGE_A(d,s,P) gload_lds16(A + ((size_t)(m0 + wid*32 + (d)*8))*K + (size_t)(s)*64 + aoff, \
                                   &As[(P)*8192 + (wid*32 + (d)*8)*64])
#define STAGE_ALL(s,P) do{ STAGE_A(0,s,P); STAGE_A(1,s,P); STAGE_A(2,s,P); STAGE_A(3,s,P); }while(0)
    // B frag loads for tile Tt into register buffer dst[4][2]
#define BLOAD(dst, Tt) do{ \
    _Pragma("unroll") \
    for(int ni=0; ni<4; ++ni) \
        _Pragma("unroll") \
        for(int ks=0; ks<2; ++ks) \
            dst[ni][ks] = Bfp[((size_t)(nf0+ni)*KS + (Tt)*2 + ks)*64 + lane]; }while(0)

#define READ_AF(s,mi) do{ \
    af[s][0] = *(const short8*)&Ap[(mi)*1024 + lr*64 + ((quad^sx)*8)]; \
    af[s][1] = *(const short8*)&Ap[(mi)*1024 + lr*64 + (((4+quad)^sx)*8)]; }while(0)
#define MFMA_MI(mi,s,bq) do{ \
    _Pragma("unroll") \
    for(int ks=0; ks<2; ++ks) \
        _Pragma("unroll") \
        for(int ni=0; ni<4; ++ni) \
            acc[mi][ni] = __builtin_amdgcn_mfma_f32_16x16x32_bf16( \
                af[s][ks], bq[ni][ks], acc[mi][ni], 0, 0, 0); }while(0)

    short8 bqA[4][2], bqB[4][2];

    // ---- prologue: stage A(0)->p0, B(0)->bqA; wait A landed (B stays in flight) ----
    STAGE_ALL(0,0);
    __builtin_amdgcn_sched_barrier(0);
    BLOAD(bqA, 0);
    __builtin_amdgcn_sched_barrier(0);
    asm volatile("s_waitcnt vmcnt(8)" ::: "memory");
    __builtin_amdgcn_s_barrier();

    for(int tt=0; tt<nt; tt+=2){
        // ================= even tile T=tt: parity 0, consume bqA =================
        {
            const int T = tt;
            STAGE_ALL(T+1, 1);                       // 4 DMAs (always valid: tt+1 < nt)
            __builtin_amdgcn_sched_barrier(0);
            BLOAD(bqB, T+1);                         // 8 B loads
            __builtin_amdgcn_sched_barrier(0);

            const unsigned short* Ap = &As[0];
            short8 af[4][2];
            READ_AF(0,0); READ_AF(1,1);
            __builtin_amdgcn_s_setprio(1);
            MFMA_MI(0,0,bqA); READ_AF(2,2);
            MFMA_MI(1,1,bqA); READ_AF(3,3);
            MFMA_MI(2,2,bqA); READ_AF(0,4);
            MFMA_MI(3,3,bqA); READ_AF(1,5);
            MFMA_MI(4,0,bqA); READ_AF(2,6);
            MFMA_MI(5,1,bqA); READ_AF(3,7);
            MFMA_MI(6,2,bqA); MFMA_MI(7,3,bqA);
            __builtin_amdgcn_s_setprio(0);

            asm volatile("s_waitcnt vmcnt(8)" ::: "memory");   // A-DMA(T+1) landed; B in flight
            __builtin_amdgcn_s_barrier();
        }
        // ================= odd tile T=tt+1: parity 1, consume bqB =================
        {
            const int T = tt+1;
            const bool more = (T+1 < nt);
            if(more){
                STAGE_ALL(T+1, 0);
                __builtin_amdgcn_sched_barrier(0);
                BLOAD(bqA, T+1);
                __builtin_amdgcn_sched_barrier(0);
            }
            const unsigned short* Ap = &As[8192];
            short8 af[4][2];
            READ_AF(0,0); READ_AF(1,1);
            __builtin_amdgcn_s_setprio(1);
            MFMA_MI(0,0,bqB); READ_AF(2,2);
            MFMA_MI(1,1,bqB); READ_AF(3,3);
            MFMA_MI(2,2,bqB); READ_AF(0,4);
            MFMA_MI(3,3,bqB); READ_AF(1,5);
            MFMA_MI(4,0,bqB); READ_AF(2,6);
            MFMA_MI(5,1,bqB); READ_AF(3,7);
            MFMA_MI(6,2,bqB); MFMA_MI(7,3,bqB);
            __builtin_amdgcn_s_setprio(0);

            if(more){
                asm volatile("s_waitcnt vmcnt(8)" ::: "memory");
                __builtin_amdgcn_s_barrier();
            }
        }
    }
#undef STAGE_A
#undef STAGE_ALL
#undef BLOAD
#undef READ_AF
#undef MFMA_MI

    // epilogue: C/D layout col(n)=lane&15, row(m)=quad*4+reg (m89/m91-verified)
    #pragma unroll
    for(int ni=0; ni<4; ++ni){
        const int n = n0 + wid*64 + ni*16 + lr;
        float bsum = 0.f;
        #pragma unroll
        for(int r=0; r<BIAS_ROWS; ++r) bsum += bias[(size_t)r*N + n];
        #pragma unroll
        for(int Q=0; Q<8; ++Q){
            #pragma unroll
            for(int reg=0; reg<4; ++reg){
                const int m = m0 + Q*16 + quad*4 + reg;
                float v = acc[Q][ni][reg] + bsum;
                if(ACT==1)      v = fmaxf(v, 0.f);
                else if(ACT==2) v = tanhf(v);
                if constexpr (F32OUT) ((float*)Cv)[(size_t)m*N + n] = v;
                else                  ((unsigned short*)Cv)[(size_t)m*N + n] = f2bf(v);
            }
        }
    }
}

extern "C" void kernel_launch(void* const* d_in, const int* in_sizes, int n_in,
                              void* d_out, int out_size, void* d_ws, size_t ws_size,
                              hipStream_t stream)
{
    const float* x  = (const float*)d_in[0];
    const float* Wg = (const float*)d_in[1];
    const float* We = (const float*)d_in[2];
    const float* be = (const float*)d_in[3];
    const float* W1 = (const float*)d_in[4];
    const float* b1 = (const float*)d_in[5];
    const float* W2 = (const float*)d_in[6];
    const float* b2 = (const float*)d_in[7];
    const float* Wo = (const float*)d_in[8];
    const float* bo = (const float*)d_in[9];
    float* out = (float*)d_out;

    const int M = 32768;    // B*T

    // workspace: 8 MB weights (frag-packed) + 96 MB slotA + 64 MB slotB = 168 MB
    char* w = (char*)d_ws;
    unsigned short* Wep   = (unsigned short*)w; w += (size_t)1024*1536*2;  //  3 MB
    unsigned short* W1b   = (unsigned short*)w; w += (size_t)1024*1024*2;  //  2 MB
    unsigned short* W2b   = (unsigned short*)w; w += (size_t)1024*1024*2;  //  2 MB
    unsigned short* Wob   = (unsigned short*)w; w += (size_t)512*1024*2;   //  1 MB
    unsigned short* slotA = (unsigned short*)w; w += (size_t)M*1536*2;     // 96 MB
    unsigned short* slotB = (unsigned short*)w; w += (size_t)M*1024*2;     // 64 MB
    unsigned short* u  = slotA;   // [M,1536]
    unsigned short* o1 = slotA;   // [M,1024] (u dead after GEMM-1)
    unsigned short* he = slotB;   // [M,1024]
    unsigned short* o2 = slotB;   // [M,1024] (he dead after GEMM-2)

    hipLaunchKernelGGL(prep, dim3(10240), dim3(256), 0, stream,
                       x, Wg, W1, W2, Wo, We, u, W1b, W2b, Wob, Wep);

    // grids: (M/128)*(N/256); all %8 == 0 for the XCD swizzle
    hipLaunchKernelGGL((gemm_bd<1,3,false>), dim3((M/128)*(1024/256)), dim3(256), 0, stream,
                       u,  Wep, be, he,  M, 1024, 1536);
    hipLaunchKernelGGL((gemm_bd<2,1,false>), dim3((M/128)*(1024/256)), dim3(256), 0, stream,
                       he, W1b, b1, o1,  M, 1024, 1024);
    hipLaunchKernelGGL((gemm_bd<2,1,false>), dim3((M/128)*(1024/256)), dim3(256), 0, stream,
                       o1, W2b, b2, o2,  M, 1024, 1024);
    hipLaunchKernelGGL((gemm_bd<0,1,true>),  dim3((M/128)*(512/256)),  dim3(256), 0, stream,
                       o2, Wob, bo, out, M, 512, 1024);
}